// Round 4
// baseline (2382.361 us; speedup 1.0000x reference)
//
#include <hip/hip_runtime.h>

// Problem constants: N=2, T=S=1024, B=4, E=1024, H=16, HD=64
// d_in order: query[T,B,E], keys[N,S,B,E], masks[N,B,S](int), Wq[N,E,E], bq[N,E],
//             Wk[N,E,E], bk[N,E], Wv[N,E,E], bv[N,E], Wo[E,E], bo[E]

// ---------------------------------------------------------------------------
// GEMM core: C[row,col] = (sum_e X[row,e] * W[col,e] + bias[col]) * scale
// X: [4096 x 1024] row-major, W: [1024 x 1024] row-major (computes X @ W^T).
// 128x128 block tile, BK=16, 256 threads, 8x8 per-thread accumulator.
// LDS pad 132: transposed stores are 2-way (free), reads broadcast/2-way (free).
// ---------------------------------------------------------------------------
template <int MODE>  // 0 = scatter into attention layout, 2 = plain row-major
__device__ __forceinline__ void gemm_body(const float* __restrict__ X,
                                          const float* __restrict__ W,
                                          const float* __restrict__ bias,
                                          float* __restrict__ out, int n,
                                          float scale) {
  __shared__ __align__(16) float Xs[16][132];
  __shared__ __align__(16) float Ws[16][132];
  const int tid = threadIdx.x;
  const int tx = tid & 15, ty = tid >> 4;
  const int row0 = blockIdx.x * 128, col0 = blockIdx.y * 128;

  float acc[8][8] = {};

  for (int k0 = 0; k0 < 1024; k0 += 16) {
#pragma unroll
    for (int p = 0; p < 2; ++p) {
      const int idx = tid + p * 256;       // float4 slot 0..511
      const int r = idx >> 2;              // tile row 0..127
      const int kc = (idx & 3) << 2;       // k sub-offset 0,4,8,12
      float4 xv = *(const float4*)&X[(long)(row0 + r) * 1024 + k0 + kc];
      float4 wv = *(const float4*)&W[(long)(col0 + r) * 1024 + k0 + kc];
      Xs[kc + 0][r] = xv.x; Xs[kc + 1][r] = xv.y;
      Xs[kc + 2][r] = xv.z; Xs[kc + 3][r] = xv.w;
      Ws[kc + 0][r] = wv.x; Ws[kc + 1][r] = wv.y;
      Ws[kc + 2][r] = wv.z; Ws[kc + 3][r] = wv.w;
    }
    __syncthreads();
#pragma unroll
    for (int kk = 0; kk < 16; ++kk) {
      float4 a0 = *(const float4*)&Xs[kk][(ty << 2)];
      float4 a1 = *(const float4*)&Xs[kk][(ty << 2) + 64];
      float4 b0 = *(const float4*)&Ws[kk][(tx << 2)];
      float4 b1 = *(const float4*)&Ws[kk][(tx << 2) + 64];
      float av[8] = {a0.x, a0.y, a0.z, a0.w, a1.x, a1.y, a1.z, a1.w};
      float bv[8] = {b0.x, b0.y, b0.z, b0.w, b1.x, b1.y, b1.z, b1.w};
#pragma unroll
      for (int i = 0; i < 8; ++i)
#pragma unroll
        for (int j = 0; j < 8; ++j) acc[i][j] += av[i] * bv[j];
    }
    __syncthreads();
  }

#pragma unroll
  for (int i = 0; i < 8; ++i) {
    const int row = row0 + (ty << 2) + (i & 3) + ((i >> 2) << 6);
#pragma unroll
    for (int j = 0; j < 8; ++j) {
      const int col = col0 + (tx << 2) + (j & 3) + ((j >> 2) << 6);
      float v = (acc[i][j] + bias[col]) * scale;
      if (MODE == 2) {
        out[(long)row * 1024 + col] = v;
      } else {
        const int t = row >> 2, bb = row & 3;   // row = t*B + b, B=4
        const int h = col >> 6, d = col & 63;   // col = h*64 + d
        out[((((long)n * 4 + bb) * 16 + h) * 1024 + t) * 64 + d] = v;
      }
    }
  }
}

// Fused q/k/v projections for both sources. blockIdx.z = 0..5:
//   n = z & 1, type = z >> 1 (0=q -> qp scaled, 1=k -> kp, 2=v -> vp)
__global__ __launch_bounds__(256) void proj_fused(const float* __restrict__ query,
                                                  const float* __restrict__ keys,
                                                  const float* __restrict__ Wq,
                                                  const float* __restrict__ bq,
                                                  const float* __restrict__ Wk,
                                                  const float* __restrict__ bk,
                                                  const float* __restrict__ Wv,
                                                  const float* __restrict__ bv,
                                                  float* __restrict__ qp,
                                                  float* __restrict__ kp,
                                                  float* __restrict__ vp) {
  const int z = blockIdx.z;
  const int n = z & 1, type = z >> 1;
  const float* X = (type == 0) ? query : keys + ((long)n << 22);  // keys + n*S*B*E
  const float* W = ((type == 0) ? Wq : (type == 1) ? Wk : Wv) + ((long)n << 20);
  const float* bias = ((type == 0) ? bq : (type == 1) ? bk : bv) + n * 1024;
  float* out = (type == 0) ? qp : (type == 1) ? kp : vp;
  const float scale = (type == 0) ? 0.125f : 1.0f;  // HD^-0.5 on q only
  gemm_body<0>(X, W, bias, out, n, scale);
}

__global__ __launch_bounds__(256) void gemm_out(const float* __restrict__ X,
                                                const float* __restrict__ W,
                                                const float* __restrict__ bias,
                                                float* __restrict__ out) {
  gemm_body<2>(X, W, bias, out, 0, 1.0f);
}

// ---------------------------------------------------------------------------
// Flash attention over concatenated sources (n=0,1), online softmax.
// One thread per query row. Grid: (T/256, H, B), block 256.
// qp/kp/vp layout: [(n*4+b)*16+h][seq][64]
// masks: int[N,B,S], nonzero = padded (-inf score)
// ao: [t*4+b][h*64+d]  (row-major 4096x1024)
// ---------------------------------------------------------------------------
__global__ __launch_bounds__(256, 1) void attn_flash(const float* __restrict__ qp,
                                                     const float* __restrict__ kp,
                                                     const float* __restrict__ vp,
                                                     const int* __restrict__ masks,
                                                     float* __restrict__ ao) {
  __shared__ __align__(16) float Ks[32][68];
  __shared__ __align__(16) float Vs[32][68];
  __shared__ float mb[32];

  const int tid = threadIdx.x;
  const int b = blockIdx.z, h = blockIdx.y;
  const int t = blockIdx.x * 256 + tid;

  float m = -3.0e38f, l = 0.0f;
  float acc[64];
#pragma unroll
  for (int d = 0; d < 64; ++d) acc[d] = 0.0f;

  for (int n = 0; n < 2; ++n) {
    float q[64];
    {
      const float* qrow = qp + ((((long)n * 4 + b) * 16 + h) * 1024 + t) * 64;
#pragma unroll
      for (int d4 = 0; d4 < 16; ++d4) {
        float4 v = *(const float4*)&qrow[d4 * 4];
        q[d4 * 4 + 0] = v.x; q[d4 * 4 + 1] = v.y;
        q[d4 * 4 + 2] = v.z; q[d4 * 4 + 3] = v.w;
      }
    }
    const float* kbase = kp + ((((long)n * 4 + b) * 16 + h) * 1024) * 64;
    const float* vbase = vp + ((((long)n * 4 + b) * 16 + h) * 1024) * 64;
    const int* mrow = masks + ((long)n * 4 + b) * 1024;

    for (int s0 = 0; s0 < 1024; s0 += 32) {
      __syncthreads();  // previous tile fully consumed
#pragma unroll
      for (int rep = 0; rep < 2; ++rep) {
        const int idx = tid + rep * 256;      // float4 index 0..511
        const int j = idx >> 4;               // key row 0..31
        const int dd = (idx & 15) << 2;       // 0..60
        *(float4*)&Ks[j][dd] = *(const float4*)&kbase[(long)(s0 + j) * 64 + dd];
        *(float4*)&Vs[j][dd] = *(const float4*)&vbase[(long)(s0 + j) * 64 + dd];
      }
      if (tid < 32) mb[tid] = mrow[s0 + tid] ? -3.0e38f : 0.0f;
      __syncthreads();

      float sc[32];
#pragma unroll 4
      for (int j = 0; j < 32; ++j) {
        float s0a = 0.f, s1a = 0.f, s2a = 0.f, s3a = 0.f;
#pragma unroll
        for (int dd = 0; dd < 64; dd += 4) {
          float4 kv = *(const float4*)&Ks[j][dd];
          s0a += q[dd + 0] * kv.x; s1a += q[dd + 1] * kv.y;
          s2a += q[dd + 2] * kv.z; s3a += q[dd + 3] * kv.w;
        }
        sc[j] = (s0a + s1a) + (s2a + s3a) + mb[j];
      }
      float mt = sc[0];
#pragma unroll
      for (int j = 1; j < 32; ++j) mt = fmaxf(mt, sc[j]);
      const float mnew = fmaxf(m, mt);
      const float corr = __expf(m - mnew);
      l *= corr;
#pragma unroll
      for (int d = 0; d < 64; ++d) acc[d] *= corr;
#pragma unroll
      for (int j = 0; j < 32; ++j) {
        sc[j] = __expf(sc[j] - mnew);
        l += sc[j];
      }
#pragma unroll 4
      for (int j = 0; j < 32; ++j) {
        const float pj = sc[j];
#pragma unroll
        for (int dd = 0; dd < 64; dd += 4) {
          float4 vv = *(const float4*)&Vs[j][dd];
          acc[dd + 0] += pj * vv.x; acc[dd + 1] += pj * vv.y;
          acc[dd + 2] += pj * vv.z; acc[dd + 3] += pj * vv.w;
        }
      }
      m = mnew;
    }
  }

  const float inv = 1.0f / l;
  float* orow = ao + ((long)t * 4 + b) * 1024 + h * 64;
#pragma unroll
  for (int dd = 0; dd < 64; dd += 4) {
    float4 o;
    o.x = acc[dd + 0] * inv; o.y = acc[dd + 1] * inv;
    o.z = acc[dd + 2] * inv; o.w = acc[dd + 3] * inv;
    *(float4*)&orow[dd] = o;
  }
}

// ---------------------------------------------------------------------------
extern "C" void kernel_launch(void* const* d_in, const int* in_sizes, int n_in,
                              void* d_out, int out_size, void* d_ws, size_t ws_size,
                              hipStream_t stream) {
  const float* query = (const float*)d_in[0];
  const float* keys  = (const float*)d_in[1];
  const int*   masks = (const int*)d_in[2];
  const float* Wq = (const float*)d_in[3];
  const float* bq = (const float*)d_in[4];
  const float* Wk = (const float*)d_in[5];
  const float* bk = (const float*)d_in[6];
  const float* Wv = (const float*)d_in[7];
  const float* bv = (const float*)d_in[8];
  const float* Wo = (const float*)d_in[9];
  const float* bo = (const float*)d_in[10];

  float* ws = (float*)d_ws;
  float* qp = ws;                    // N*B*H*T*HD = 8M floats
  float* kp = ws + 8388608;          // 8M floats
  float* vp = ws + 16777216;         // 8M floats
  float* ao = ws + 25165824;         // 4M floats
  // total 28M floats = 112MB of d_ws

  const dim3 blk(256);

  // fused q/k/v projections for both sources: z = type*2 + n
  proj_fused<<<dim3(32, 8, 6), blk, 0, stream>>>(query, keys, Wq, bq, Wk, bk,
                                                 Wv, bv, qp, kp, vp);
  // attention
  attn_flash<<<dim3(4, 16, 4), blk, 0, stream>>>(qp, kp, vp, masks, ao);
  // output projection
  gemm_out<<<dim3(32, 8, 1), blk, 0, stream>>>(ao, Wo, bo, (float*)d_out);
}

// Round 6
// 996.438 us; speedup vs baseline: 2.3909x; 2.3909x over previous
//
#include <hip/hip_runtime.h>

// N=2, T=S=1024, B=4, E=1024, H=16, HD=64
// d_in: query[T,B,E], keys[N,S,B,E], masks[N,B,S](int), Wq[N,E,E], bq[N,E],
//       Wk[N,E,E], bk[N,E], Wv[N,E,E], bv[N,E], Wo[E,E], bo[E]  (all fp32)

typedef __bf16 bf16x8 __attribute__((ext_vector_type(8)));
typedef unsigned short u16x8 __attribute__((ext_vector_type(8)));
typedef unsigned short u16x4 __attribute__((ext_vector_type(4)));
typedef float f32x4 __attribute__((ext_vector_type(4)));

// ws layout (ushort/bf16 element offsets); total 47M elements = 94 MB
#define OFF_QP 0ul            // [N*B*H][1024][64] bf16 q (pre-scaled by 0.125)
#define OFF_KP (8ul << 20)
#define OFF_VP (16ul << 20)
#define OFF_AO (24ul << 20)   // [4096][1024] bf16 attention output
#define OFF_XQ (28ul << 20)   // query bf16 [4096][1024]
#define OFF_XK (32ul << 20)   // keys bf16 [2][4096][1024]
#define OFF_W (40ul << 20)    // Wq(2M) Wk(2M) Wv(2M) bf16
#define OFF_WO (46ul << 20)   // Wo bf16 (1M)

__device__ __forceinline__ unsigned short f2bf(float x) {
  unsigned u = __builtin_bit_cast(unsigned, x);
  return (unsigned short)((u + 0x7fffu + ((u >> 16) & 1u)) >> 16);
}
__device__ __forceinline__ float bf2f(unsigned short h) {
  return __builtin_bit_cast(float, (unsigned)h << 16);
}
__device__ __forceinline__ void gload16(const void* g, void* l) {
  __builtin_amdgcn_global_load_lds(
      (const __attribute__((address_space(1))) unsigned*)g,
      (__attribute__((address_space(3))) unsigned*)l, 16, 0, 0);
}

// ---------------------------------------------------------------------------
// fp32 -> bf16 conversions, one launch, blockIdx.y picks region
// ---------------------------------------------------------------------------
__global__ __launch_bounds__(256) void cvt_all(
    const float* __restrict__ q, const float* __restrict__ k,
    const float* __restrict__ wq, const float* __restrict__ wk,
    const float* __restrict__ wv, const float* __restrict__ wo,
    unsigned short* __restrict__ ws) {
  const int z = blockIdx.y;
  const float* src;
  unsigned short* dst;
  unsigned nq;  // float4 count
  if (z == 0)      { src = q;  dst = ws + OFF_XQ;              nq = 1u << 20; }
  else if (z == 1) { src = k;  dst = ws + OFF_XK;              nq = 2u << 20; }
  else if (z == 2) { src = wq; dst = ws + OFF_W;               nq = 1u << 19; }
  else if (z == 3) { src = wk; dst = ws + OFF_W + (2ul << 20); nq = 1u << 19; }
  else if (z == 4) { src = wv; dst = ws + OFF_W + (4ul << 20); nq = 1u << 19; }
  else             { src = wo; dst = ws + OFF_WO;              nq = 1u << 18; }
  for (unsigned i = blockIdx.x * 256 + threadIdx.x; i < nq; i += gridDim.x * 256) {
    float4 v = ((const float4*)src)[i];
    u16x4 o = {f2bf(v.x), f2bf(v.y), f2bf(v.z), f2bf(v.w)};
    *(u16x4*)&dst[(size_t)i * 4] = o;
  }
}

// ---------------------------------------------------------------------------
// bf16 MFMA GEMM (m97 structure): C[m,n] = sum_k A[m,k]*B[n,k], fp32 accum.
// A [Mx1024], B [1024x1024], both K-contiguous bf16. 128x128 tile, BK=32,
// 256 thr = 4 waves (2x2), each wave 64x64 = 4x4 frags of 16x16x32.
// LDS slab layout: slab kb (k-octet) holds 128 rows x 8 bf16 -> frag reads
// are 2-way-aliased max (free); global_load_lds dest is linear per wave.
// ---------------------------------------------------------------------------
template <int MODE>  // 0: scatter bf16 to attention layout; 2: fp32 row-major
__device__ __forceinline__ void gemm_mfma(const unsigned short* __restrict__ A,
                                          const unsigned short* __restrict__ B,
                                          const float* __restrict__ bias,
                                          void* __restrict__ outp, int nsrc,
                                          float scale) {
  __shared__ unsigned short As[4096];  // [4 slabs][128 rows][8]
  __shared__ unsigned short Bs[4096];
  const int tid = threadIdx.x;
  const int w = tid >> 6, lane = tid & 63;
  const int wr = w >> 1, wc = w & 1;
  const long row0 = (long)blockIdx.x * 128, col0 = (long)blockIdx.y * 128;

  f32x4 acc[4][4] = {};

  // staging: wave w loads k-octet w (16B per lane per row), halves h=0,1
  const unsigned short* ga0 = A + (row0 + lane) * 1024 + w * 8;
  const unsigned short* ga1 = ga0 + 64 * 1024;
  const unsigned short* gb0 = B + (col0 + lane) * 1024 + w * 8;
  const unsigned short* gb1 = gb0 + 64 * 1024;
  unsigned short* la0 = &As[w * 1024];
  unsigned short* la1 = la0 + 512;
  unsigned short* lb0 = &Bs[w * 1024];
  unsigned short* lb1 = lb0 + 512;

  const int kb = (lane >> 4) * 1024;  // slab base for this lane's k-octet
  const int fr = lane & 15;

  for (int k0 = 0; k0 < 1024; k0 += 32) {
    gload16(ga0 + k0, la0);
    gload16(ga1 + k0, la1);
    gload16(gb0 + k0, lb0);
    gload16(gb1 + k0, lb1);
    __syncthreads();  // drains vmcnt -> staged data visible
    bf16x8 af[4], bfr[4];
#pragma unroll
    for (int m = 0; m < 4; ++m)
      af[m] = __builtin_bit_cast(
          bf16x8, *(const u16x8*)&As[kb + (wr * 64 + m * 16 + fr) * 8]);
#pragma unroll
    for (int nn = 0; nn < 4; ++nn)
      bfr[nn] = __builtin_bit_cast(
          bf16x8, *(const u16x8*)&Bs[kb + (wc * 64 + nn * 16 + fr) * 8]);
#pragma unroll
    for (int m = 0; m < 4; ++m)
#pragma unroll
      for (int nn = 0; nn < 4; ++nn)
        acc[m][nn] = __builtin_amdgcn_mfma_f32_16x16x32_bf16(af[m], bfr[nn],
                                                             acc[m][nn], 0, 0, 0);
    __syncthreads();  // all waves done reading before next-stage overwrite
  }

  // epilogue; C/D layout: col = lane&15, row = (lane>>4)*4 + reg
  const int fq = lane >> 4;
#pragma unroll
  for (int m = 0; m < 4; ++m)
#pragma unroll
    for (int nn = 0; nn < 4; ++nn) {
      const long col = col0 + wc * 64 + nn * 16 + fr;
      const float bcol = bias[col];
#pragma unroll
      for (int r = 0; r < 4; ++r) {
        const long row = row0 + wr * 64 + m * 16 + fq * 4 + r;
        const float v = (acc[m][nn][r] + bcol) * scale;
        if (MODE == 2) {
          ((float*)outp)[row * 1024 + col] = v;
        } else {
          const long t = row >> 2, bb = row & 3;  // row = t*4 + b
          const long h = col >> 6, d = col & 63;  // col = h*64 + d
          ((unsigned short*)outp)[((((long)nsrc * 4 + bb) * 16 + h) * 1024 + t) * 64 + d] =
              f2bf(v);
        }
      }
    }
}

// fused q/k/v projections, blockIdx.z = type*2 + n
__global__ __launch_bounds__(256) void proj_fused(unsigned short* __restrict__ ws,
                                                  const float* __restrict__ bq,
                                                  const float* __restrict__ bk,
                                                  const float* __restrict__ bv) {
  const int z = blockIdx.z;
  const int n = z & 1, type = z >> 1;
  const unsigned short* A = ws + (type == 0 ? OFF_XQ : OFF_XK + (unsigned long)n * (4ul << 20));
  const unsigned short* B = ws + OFF_W + (unsigned long)(type * 2 + n) * (1ul << 20);
  const float* bias = ((type == 0) ? bq : (type == 1) ? bk : bv) + n * 1024;
  unsigned short* out = ws + (type == 0 ? OFF_QP : (type == 1) ? OFF_KP : OFF_VP);
  const float scale = (type == 0) ? 0.125f : 1.0f;
  gemm_mfma<0>(A, B, bias, out, n, scale);
}

__global__ __launch_bounds__(256) void gemm_out(const unsigned short* __restrict__ ws_c,
                                                const float* __restrict__ bias,
                                                float* __restrict__ out) {
  gemm_mfma<2>(ws_c + OFF_AO, ws_c + OFF_WO, bias, out, 0, 1.0f);
}

// ---------------------------------------------------------------------------
// Flash attention, 4 threads per query row (16 dims each), quad shuffle-reduce
// for scores. Block 256 = 64 rows; grid (16, H, B) = 1024 blocks -> 4 waves/SIMD.
// qp/kp/vp: bf16 [(n*4+b)*16+h][seq][64]; masks int[N,B,S] nonzero = pad.
// ao: bf16 [t*4+b][h*64+d]
// ---------------------------------------------------------------------------
__global__ __launch_bounds__(256, 4) void attn_flash(
    const unsigned short* __restrict__ qp, const unsigned short* __restrict__ kp,
    const unsigned short* __restrict__ vp, const int* __restrict__ masks,
    unsigned short* __restrict__ ao) {
  __shared__ __align__(16) float Ks[32][68];
  __shared__ __align__(16) float Vs[32][68];
  __shared__ float mb[32];

  const int tid = threadIdx.x;
  const int b = blockIdx.z, h = blockIdx.y;
  const int rl = tid >> 2, sub = tid & 3;
  const int t = blockIdx.x * 64 + rl;
  const int d0 = sub * 16;

  float m = -3.0e38f, l = 0.0f;
  float acc[16];
#pragma unroll
  for (int d = 0; d < 16; ++d) acc[d] = 0.0f;

  for (int n = 0; n < 2; ++n) {
    float q[16];
    {
      const unsigned short* qrow =
          qp + ((((long)n * 4 + b) * 16 + h) * 1024 + t) * 64 + d0;
      u16x8 q0 = *(const u16x8*)&qrow[0];
      u16x8 q1 = *(const u16x8*)&qrow[8];
#pragma unroll
      for (int i = 0; i < 8; ++i) { q[i] = bf2f(q0[i]); q[8 + i] = bf2f(q1[i]); }
    }
    const unsigned short* kbase = kp + (((long)n * 4 + b) * 16 + h) * 1024 * 64;
    const unsigned short* vbase = vp + (((long)n * 4 + b) * 16 + h) * 1024 * 64;
    const int* mrow = masks + ((long)n * 4 + b) * 1024;
    const int js = tid >> 3, d8 = (tid & 7) * 8;

    for (int s0 = 0; s0 < 1024; s0 += 32) {
      __syncthreads();  // previous tile fully consumed
      {
        u16x8 kv = *(const u16x8*)&kbase[(long)(s0 + js) * 64 + d8];
        u16x8 vv = *(const u16x8*)&vbase[(long)(s0 + js) * 64 + d8];
#pragma unroll
        for (int e = 0; e < 8; ++e) {
          Ks[js][d8 + e] = bf2f(kv[e]);
          Vs[js][d8 + e] = bf2f(vv[e]);
        }
        if (tid < 32) mb[tid] = mrow[s0 + tid] ? -3.0e38f : 0.0f;
      }
      __syncthreads();

      float sc[32];
#pragma unroll
      for (int j = 0; j < 32; ++j) {
        f32x4 k0v = *(const f32x4*)&Ks[j][d0];
        f32x4 k1v = *(const f32x4*)&Ks[j][d0 + 4];
        f32x4 k2v = *(const f32x4*)&Ks[j][d0 + 8];
        f32x4 k3v = *(const f32x4*)&Ks[j][d0 + 12];
        float p = 0.f;
#pragma unroll
        for (int e = 0; e < 4; ++e)
          p += q[e] * k0v[e] + q[4 + e] * k1v[e] + q[8 + e] * k2v[e] +
               q[12 + e] * k3v[e];
        p += __shfl_xor(p, 1, 64);  // quad reduce: all 4 lanes get full dot
        p += __shfl_xor(p, 2, 64);
        sc[j] = p + mb[j];
      }
      float mt = sc[0];
#pragma unroll
      for (int j = 1; j < 32; ++j) mt = fmaxf(mt, sc[j]);
      const float mnew = fmaxf(m, mt);
      const float corr = __expf(m - mnew);
      l *= corr;
#pragma unroll
      for (int d = 0; d < 16; ++d) acc[d] *= corr;
#pragma unroll
      for (int j = 0; j < 32; ++j) {
        sc[j] = __expf(sc[j] - mnew);
        l += sc[j];
      }
#pragma unroll
      for (int j = 0; j < 32; ++j) {
        const float pj = sc[j];
        f32x4 v0 = *(const f32x4*)&Vs[j][d0];
        f32x4 v1 = *(const f32x4*)&Vs[j][d0 + 4];
        f32x4 v2 = *(const f32x4*)&Vs[j][d0 + 8];
        f32x4 v3 = *(const f32x4*)&Vs[j][d0 + 12];
#pragma unroll
        for (int e = 0; e < 4; ++e) {
          acc[e] += pj * v0[e];
          acc[4 + e] += pj * v1[e];
          acc[8 + e] += pj * v2[e];
          acc[12 + e] += pj * v3[e];
        }
      }
      m = mnew;
    }
  }

  const float inv = 1.0f / l;
  unsigned short* orow = ao + ((long)t * 4 + b) * 1024 + h * 64 + d0;
  u16x8 o0, o1;
#pragma unroll
  for (int i = 0; i < 8; ++i) {
    o0[i] = f2bf(acc[i] * inv);
    o1[i] = f2bf(acc[8 + i] * inv);
  }
  *(u16x8*)&orow[0] = o0;
  *(u16x8*)&orow[8] = o1;
}

// ---------------------------------------------------------------------------
extern "C" void kernel_launch(void* const* d_in, const int* in_sizes, int n_in,
                              void* d_out, int out_size, void* d_ws, size_t ws_size,
                              hipStream_t stream) {
  const float* query = (const float*)d_in[0];
  const float* keys = (const float*)d_in[1];
  const int* masks = (const int*)d_in[2];
  const float* Wq = (const float*)d_in[3];
  const float* bq = (const float*)d_in[4];
  const float* Wk = (const float*)d_in[5];
  const float* bk = (const float*)d_in[6];
  const float* Wv = (const float*)d_in[7];
  const float* bv = (const float*)d_in[8];
  const float* Wo = (const float*)d_in[9];
  const float* bo = (const float*)d_in[10];

  unsigned short* ws = (unsigned short*)d_ws;  // 94 MB used
  const dim3 blk(256);

  // fp32 -> bf16 for activations + weights
  cvt_all<<<dim3(512, 6), blk, 0, stream>>>(query, keys, Wq, Wk, Wv, Wo, ws);
  // fused q/k/v MFMA projections (writes bf16 attention-layout q/k/v)
  proj_fused<<<dim3(32, 8, 6), blk, 0, stream>>>(ws, bq, bk, bv);
  // flash attention (writes bf16 ao)
  attn_flash<<<dim3(16, 16, 4), blk, 0, stream>>>(
      ws + OFF_QP, ws + OFF_KP, ws + OFF_VP, masks, ws + OFF_AO);
  // output projection (fp32 out + bias)
  gemm_out<<<dim3(32, 8, 1), blk, 0, stream>>>(ws, bo, (float*)d_out);
}

// Round 8
// 361.186 us; speedup vs baseline: 6.5959x; 2.7588x over previous
//
#include <hip/hip_runtime.h>

// N=2, T=S=1024, B=4, E=1024, H=16, HD=64
// d_in: query[T,B,E], keys[N,S,B,E], masks[N,B,S](int), Wq[N,E,E], bq[N,E],
//       Wk[N,E,E], bk[N,E], Wv[N,E,E], bv[N,E], Wo[E,E], bo[E]  (all fp32)

typedef __bf16 bf16x8 __attribute__((ext_vector_type(8)));
typedef unsigned short u16x8 __attribute__((ext_vector_type(8)));
typedef unsigned short u16x4 __attribute__((ext_vector_type(4)));
typedef float f32x4 __attribute__((ext_vector_type(4)));

// ws layout (ushort element offsets); total 47M elements = 94 MB
#define OFF_QP 0ul            // [N*B*H][1024 t][64 d] bf16 q (pre-scaled 0.125)
#define OFF_KP (8ul << 20)    // [N*B*H][1024 s][64 d] bf16 k
#define OFF_VP (16ul << 20)   // [N*B*H][64 d][1024 s] bf16 v  (d-major!)
#define OFF_AO (24ul << 20)   // [4096][1024] bf16 attention output
#define OFF_XQ (28ul << 20)   // query bf16 [4096][1024]
#define OFF_XK (32ul << 20)   // keys bf16 [2][4096][1024]
#define OFF_W (40ul << 20)    // Wq(2M) Wk(2M) Wv(2M) bf16
#define OFF_WO (46ul << 20)   // Wo bf16 (1M)

__device__ __forceinline__ unsigned short f2bf(float x) {
  unsigned u = __builtin_bit_cast(unsigned, x);
  return (unsigned short)((u + 0x7fffu + ((u >> 16) & 1u)) >> 16);
}
__device__ __forceinline__ float bf2f(unsigned short h) {
  return __builtin_bit_cast(float, (unsigned)h << 16);
}
__device__ __forceinline__ void gload16(const void* g, void* l) {
  __builtin_amdgcn_global_load_lds(
      (const __attribute__((address_space(1))) unsigned*)g,
      (__attribute__((address_space(3))) unsigned*)l, 16, 0, 0);
}

// ---------------------------------------------------------------------------
// fp32 -> bf16 conversions, one launch, blockIdx.y picks region
// ---------------------------------------------------------------------------
__global__ __launch_bounds__(256) void cvt_all(
    const float* __restrict__ q, const float* __restrict__ k,
    const float* __restrict__ wq, const float* __restrict__ wk,
    const float* __restrict__ wv, const float* __restrict__ wo,
    unsigned short* __restrict__ ws) {
  const int z = blockIdx.y;
  const float* src;
  unsigned short* dst;
  unsigned nq;  // float4 count
  if (z == 0)      { src = q;  dst = ws + OFF_XQ;              nq = 1u << 20; }
  else if (z == 1) { src = k;  dst = ws + OFF_XK;              nq = 2u << 20; }
  else if (z == 2) { src = wq; dst = ws + OFF_W;               nq = 1u << 19; }
  else if (z == 3) { src = wk; dst = ws + OFF_W + (2ul << 20); nq = 1u << 19; }
  else if (z == 4) { src = wv; dst = ws + OFF_W + (4ul << 20); nq = 1u << 19; }
  else             { src = wo; dst = ws + OFF_WO;              nq = 1u << 18; }
  for (unsigned i = blockIdx.x * 256 + threadIdx.x; i < nq; i += gridDim.x * 256) {
    float4 v = ((const float4*)src)[i];
    u16x4 o = {f2bf(v.x), f2bf(v.y), f2bf(v.z), f2bf(v.w)};
    *(u16x4*)&dst[(size_t)i * 4] = o;
  }
}

// ---------------------------------------------------------------------------
// bf16 MFMA GEMM (validated r6): C[m,n] = sum_k A[m,k]*B[n,k], fp32 accum.
// 128x128 tile, BK=32, 4 waves (2x2), per-wave 64x64 = 4x4 frags 16x16x32.
// mode 0: bf16 scatter [nbh][seq][64]; mode 1: bf16 d-major [nbh][64][1024];
// mode 2: fp32 row-major.
// ---------------------------------------------------------------------------
__device__ __forceinline__ void gemm_mfma(const unsigned short* __restrict__ A,
                                          const unsigned short* __restrict__ B,
                                          const float* __restrict__ bias,
                                          void* __restrict__ outp, int nsrc,
                                          float scale, int mode) {
  __shared__ unsigned short As[4096];  // [4 k-octet slabs][128 rows][8]
  __shared__ unsigned short Bs[4096];
  const int tid = threadIdx.x;
  const int w = tid >> 6, lane = tid & 63;
  const int wr = w >> 1, wc = w & 1;
  const long row0 = (long)blockIdx.x * 128, col0 = (long)blockIdx.y * 128;

  f32x4 acc[4][4] = {};

  const unsigned short* ga0 = A + (row0 + lane) * 1024 + w * 8;
  const unsigned short* ga1 = ga0 + 64 * 1024;
  const unsigned short* gb0 = B + (col0 + lane) * 1024 + w * 8;
  const unsigned short* gb1 = gb0 + 64 * 1024;
  unsigned short* la0 = &As[w * 1024];
  unsigned short* la1 = la0 + 512;
  unsigned short* lb0 = &Bs[w * 1024];
  unsigned short* lb1 = lb0 + 512;

  const int kb = (lane >> 4) * 1024;
  const int fr = lane & 15;

  for (int k0 = 0; k0 < 1024; k0 += 32) {
    gload16(ga0 + k0, la0);
    gload16(ga1 + k0, la1);
    gload16(gb0 + k0, lb0);
    gload16(gb1 + k0, lb1);
    __syncthreads();
    bf16x8 af[4], bfr[4];
#pragma unroll
    for (int m = 0; m < 4; ++m)
      af[m] = __builtin_bit_cast(
          bf16x8, *(const u16x8*)&As[kb + (wr * 64 + m * 16 + fr) * 8]);
#pragma unroll
    for (int nn = 0; nn < 4; ++nn)
      bfr[nn] = __builtin_bit_cast(
          bf16x8, *(const u16x8*)&Bs[kb + (wc * 64 + nn * 16 + fr) * 8]);
#pragma unroll
    for (int m = 0; m < 4; ++m)
#pragma unroll
      for (int nn = 0; nn < 4; ++nn)
        acc[m][nn] = __builtin_amdgcn_mfma_f32_16x16x32_bf16(af[m], bfr[nn],
                                                             acc[m][nn], 0, 0, 0);
    __syncthreads();
  }

  const int fq = lane >> 4;
#pragma unroll
  for (int m = 0; m < 4; ++m)
#pragma unroll
    for (int nn = 0; nn < 4; ++nn) {
      const long col = col0 + wc * 64 + nn * 16 + fr;
      const float bcol = bias[col];
#pragma unroll
      for (int r = 0; r < 4; ++r) {
        const long row = row0 + wr * 64 + m * 16 + fq * 4 + r;
        const float v = (acc[m][nn][r] + bcol) * scale;
        const long t = row >> 2, bb = row & 3;  // row = t*4 + b
        const long h = col >> 6, d = col & 63;  // col = h*64 + d
        const long nbh = ((long)nsrc * 4 + bb) * 16 + h;
        if (mode == 2)
          ((float*)outp)[row * 1024 + col] = v;
        else if (mode == 0)
          ((unsigned short*)outp)[(nbh * 1024 + t) * 64 + d] = f2bf(v);
        else
          ((unsigned short*)outp)[nbh * 65536 + d * 1024 + t] = f2bf(v);
      }
    }
}

// fused q/k/v projections, blockIdx.z = type*2 + n
__global__ __launch_bounds__(256) void proj_fused(unsigned short* __restrict__ ws,
                                                  const float* __restrict__ bq,
                                                  const float* __restrict__ bk,
                                                  const float* __restrict__ bv) {
  const int z = blockIdx.z;
  const int n = z & 1, type = z >> 1;
  const unsigned short* A =
      ws + (type == 0 ? OFF_XQ : OFF_XK + (unsigned long)n * (4ul << 20));
  const unsigned short* B = ws + OFF_W + (unsigned long)(type * 2 + n) * (1ul << 20);
  const float* bias = ((type == 0) ? bq : (type == 1) ? bk : bv) + n * 1024;
  unsigned short* out = ws + (type == 0 ? OFF_QP : (type == 1) ? OFF_KP : OFF_VP);
  const float scale = (type == 0) ? 0.125f : 1.0f;
  gemm_mfma(A, B, bias, out, n, scale, (type == 2) ? 1 : 0);
}

__global__ __launch_bounds__(256) void gemm_out(const unsigned short* __restrict__ ws_c,
                                                const float* __restrict__ bias,
                                                float* __restrict__ out) {
  gemm_mfma(ws_c + OFF_AO, ws_c + OFF_WO, bias, (void*)out, 0, 1.0f, 2);
}

// ---------------------------------------------------------------------------
// MFMA flash attention. Block 256 = 4 waves; wave owns 16 q-rows.
// Grid (16, H, B). Per 64-key tile:
//   S^T = mfma(A=K[key][d], B=Q^T[d][qrow])  (swapped -> row stats via 2 shfl)
//   online softmax in-register; P -> bf16 -> per-wave LDS [16][72]
//   O^T += mfma(A=V^T[d][key], B=P^T[key][qrow])   (V staged d-major)
// qp/kp: [nbh][seq][64]; vpt: [nbh][64][1024]; masks int[N,B,S] nonzero=pad.
// ao: bf16 [t*4+b][h*64+d]
// ---------------------------------------------------------------------------
__global__ __launch_bounds__(256) void attn_mfma(
    const unsigned short* __restrict__ qp, const unsigned short* __restrict__ kp,
    const unsigned short* __restrict__ vpt, const int* __restrict__ masks,
    unsigned short* __restrict__ ao) {
  __shared__ __align__(16) unsigned short Ks[64 * 72];   // [key][72]
  __shared__ __align__(16) unsigned short Vt[64 * 72];   // [d][72]
  __shared__ __align__(16) unsigned short Pl[4 * 16 * 72];  // per-wave [q][72]
  __shared__ __align__(16) float mba[2 * 1024];          // -3e38 / 0 per key

  const int tid = threadIdx.x;
  const int w = tid >> 6, l = tid & 63;
  const int g = l >> 4, q16 = l & 15;
  const int b = blockIdx.z, h = blockIdx.y;
  const int t0 = blockIdx.x * 64 + w * 16;

  // stage masks for both sources as f32 add-terms
#pragma unroll
  for (int p = 0; p < 2; ++p) {
    const int idx = tid + p * 256;            // 0..511
    const int n = idx >> 8, off = (idx & 255) * 4;
    const int4 mi = *(const int4*)&masks[((long)n * 4 + b) * 1024 + off];
    f32x4 mf = {mi.x ? -3.0e38f : 0.0f, mi.y ? -3.0e38f : 0.0f,
                mi.z ? -3.0e38f : 0.0f, mi.w ? -3.0e38f : 0.0f};
    *(f32x4*)&mba[n * 1024 + off] = mf;
  }

  float m = -3.0e38f, ls = 0.0f;
  f32x4 o[4] = {};  // O^T d-frags: d = df*16 + g*4 + r, col = qrow

  unsigned short* pw = &Pl[(w * 16 + q16) * 72];

  for (int n = 0; n < 2; ++n) {
    const long nbh = ((long)n * 4 + b) * 16 + h;
    // Q B-frags (held in registers for the whole source)
    const unsigned short* qrp = qp + (nbh * 1024 + t0 + q16) * 64 + g * 8;
    const bf16x8 qf0 = __builtin_bit_cast(bf16x8, *(const u16x8*)&qrp[0]);
    const bf16x8 qf1 = __builtin_bit_cast(bf16x8, *(const u16x8*)&qrp[32]);
    const unsigned short* kbase = kp + nbh * 65536;
    const unsigned short* vbase = vpt + nbh * 65536;
    const float* mb = &mba[n * 1024];

    for (int s0 = 0; s0 < 1024; s0 += 64) {
      __syncthreads();  // prev tile consumed (covers mask staging on 1st iter)
      // stage K [64 keys][64 d] and V^T [64 d][64 keys]
#pragma unroll
      for (int p = 0; p < 2; ++p) {
        const int id = tid + p * 256;        // 0..511 chunks of 8 bf16
        const int r8 = id >> 3, c8 = (id & 7) * 8;
        *(u16x8*)&Ks[r8 * 72 + c8] = *(const u16x8*)&kbase[(long)(s0 + r8) * 64 + c8];
        *(u16x8*)&Vt[r8 * 72 + c8] = *(const u16x8*)&vbase[(long)r8 * 1024 + s0 + c8];
      }
      __syncthreads();

      // QK^T (swapped): S^T key-frags
      f32x4 st[4] = {};
#pragma unroll
      for (int kf = 0; kf < 4; ++kf) {
        const bf16x8 ka0 = __builtin_bit_cast(
            bf16x8, *(const u16x8*)&Ks[(kf * 16 + q16) * 72 + g * 8]);
        const bf16x8 ka1 = __builtin_bit_cast(
            bf16x8, *(const u16x8*)&Ks[(kf * 16 + q16) * 72 + 32 + g * 8]);
        st[kf] = __builtin_amdgcn_mfma_f32_16x16x32_bf16(ka0, qf0, st[kf], 0, 0, 0);
        st[kf] = __builtin_amdgcn_mfma_f32_16x16x32_bf16(ka1, qf1, st[kf], 0, 0, 0);
      }
      // mask + row max (key = kf*16 + g*4 + r, col = qrow = q16)
      float mt = -3.0e38f;
#pragma unroll
      for (int kf = 0; kf < 4; ++kf) {
        const f32x4 mv = *(const f32x4*)&mb[s0 + kf * 16 + g * 4];
#pragma unroll
        for (int r = 0; r < 4; ++r) {
          st[kf][r] += mv[r];
          mt = fmaxf(mt, st[kf][r]);
        }
      }
      mt = fmaxf(mt, __shfl_xor(mt, 16, 64));
      mt = fmaxf(mt, __shfl_xor(mt, 32, 64));
      const float mnew = fmaxf(m, mt);
      const float corr = __expf(m - mnew);
      float ps = 0.0f;
#pragma unroll
      for (int kf = 0; kf < 4; ++kf)
#pragma unroll
        for (int r = 0; r < 4; ++r) {
          st[kf][r] = __expf(st[kf][r] - mnew);
          ps += st[kf][r];
        }
      ps += __shfl_xor(ps, 16, 64);
      ps += __shfl_xor(ps, 32, 64);
      ls = ls * corr + ps;
      m = mnew;
#pragma unroll
      for (int df = 0; df < 4; ++df)
#pragma unroll
        for (int r = 0; r < 4; ++r) o[df][r] *= corr;
      // P -> bf16 -> per-wave LDS (row q16, keys kf*16 + g*4 .. +3)
#pragma unroll
      for (int kf = 0; kf < 4; ++kf) {
        u16x4 pp = {f2bf(st[kf][0]), f2bf(st[kf][1]), f2bf(st[kf][2]),
                    f2bf(st[kf][3])};
        *(u16x4*)&pw[kf * 16 + g * 4] = pp;
      }
      // PV: O^T += V^T · P^T  (k-dim 64 keys = 2 chunks)
      const bf16x8 pb0 = __builtin_bit_cast(bf16x8, *(const u16x8*)&pw[g * 8]);
      const bf16x8 pb1 = __builtin_bit_cast(bf16x8, *(const u16x8*)&pw[32 + g * 8]);
#pragma unroll
      for (int df = 0; df < 4; ++df) {
        const bf16x8 va0 = __builtin_bit_cast(
            bf16x8, *(const u16x8*)&Vt[(df * 16 + q16) * 72 + g * 8]);
        const bf16x8 va1 = __builtin_bit_cast(
            bf16x8, *(const u16x8*)&Vt[(df * 16 + q16) * 72 + 32 + g * 8]);
        o[df] = __builtin_amdgcn_mfma_f32_16x16x32_bf16(va0, pb0, o[df], 0, 0, 0);
        o[df] = __builtin_amdgcn_mfma_f32_16x16x32_bf16(va1, pb1, o[df], 0, 0, 0);
      }
    }
  }

  // epilogue: O[qrow][d], normalize; ao row = qrow*4 + b, col = h*64 + d
  const float inv = 1.0f / ls;
  unsigned short* orow = ao + ((long)(t0 + q16) * 4 + b) * 1024 + h * 64 + g * 4;
#pragma unroll
  for (int df = 0; df < 4; ++df) {
    u16x4 ov = {f2bf(o[df][0] * inv), f2bf(o[df][1] * inv),
                f2bf(o[df][2] * inv), f2bf(o[df][3] * inv)};
    *(u16x4*)&orow[df * 16] = ov;
  }
}

// ---------------------------------------------------------------------------
extern "C" void kernel_launch(void* const* d_in, const int* in_sizes, int n_in,
                              void* d_out, int out_size, void* d_ws, size_t ws_size,
                              hipStream_t stream) {
  const float* query = (const float*)d_in[0];
  const float* keys = (const float*)d_in[1];
  const int* masks = (const int*)d_in[2];
  const float* bq = (const float*)d_in[4];
  const float* bk = (const float*)d_in[6];
  const float* bv = (const float*)d_in[8];
  const float* bo = (const float*)d_in[10];

  unsigned short* ws = (unsigned short*)d_ws;  // 94 MB used
  const dim3 blk(256);

  cvt_all<<<dim3(512, 6), blk, 0, stream>>>(query, keys, (const float*)d_in[3],
                                            (const float*)d_in[5],
                                            (const float*)d_in[7],
                                            (const float*)d_in[9], ws);
  proj_fused<<<dim3(32, 8, 6), blk, 0, stream>>>(ws, bq, bk, bv);
  attn_mfma<<<dim3(16, 16, 4), blk, 0, stream>>>(
      ws + OFF_QP, ws + OFF_KP, ws + OFF_VP, masks, ws + OFF_AO);
  gemm_out<<<dim3(32, 8, 1), blk, 0, stream>>>(ws, bo, (float*)d_out);
}

// Round 12
// 356.481 us; speedup vs baseline: 6.6830x; 1.0132x over previous
//
#include <hip/hip_runtime.h>

// N=2, T=S=1024, B=4, E=1024, H=16, HD=64
// d_in: query[T,B,E], keys[N,S,B,E], masks[N,B,S](int), Wq[N,E,E], bq[N,E],
//       Wk[N,E,E], bk[N,E], Wv[N,E,E], bv[N,E], Wo[E,E], bo[E]  (all fp32)

typedef __bf16 bf16x8 __attribute__((ext_vector_type(8)));
typedef unsigned short u16x8 __attribute__((ext_vector_type(8)));
typedef unsigned short u16x4 __attribute__((ext_vector_type(4)));
typedef float f32x4 __attribute__((ext_vector_type(4)));

// ws layout (ushort element offsets); total 47M elements = 94 MB
#define OFF_QP 0ul            // [N*B*H][1024 t][64 d] bf16 q (pre-scaled 0.125)
#define OFF_KP (8ul << 20)    // [N*B*H][1024 s][64 d] bf16 k
#define OFF_VP (16ul << 20)   // [N*B*H][64 d][1024 s] bf16 v  (d-major!)
#define OFF_AO (24ul << 20)   // [4096][1024] bf16 attention output
#define OFF_XQ (28ul << 20)   // query bf16 [4096][1024]
#define OFF_XK (32ul << 20)   // keys bf16 [2][4096][1024]
#define OFF_W (40ul << 20)    // Wq(2M) Wk(2M) Wv(2M) bf16
#define OFF_WO (46ul << 20)   // Wo bf16 (1M)

__device__ __forceinline__ unsigned short f2bf(float x) {
  unsigned u = __builtin_bit_cast(unsigned, x);
  return (unsigned short)((u + 0x7fffu + ((u >> 16) & 1u)) >> 16);
}
__device__ __forceinline__ float bf2f(unsigned short h) {
  return __builtin_bit_cast(float, (unsigned)h << 16);
}
__device__ __forceinline__ void gload16(const void* g, void* l) {
  __builtin_amdgcn_global_load_lds(
      (const __attribute__((address_space(1))) unsigned*)g,
      (__attribute__((address_space(3))) unsigned*)l, 16, 0, 0);
}

// ---------------------------------------------------------------------------
// fp32 -> bf16 conversions, one launch, blockIdx.y picks region
// ---------------------------------------------------------------------------
__global__ __launch_bounds__(256) void cvt_all(
    const float* __restrict__ q, const float* __restrict__ k,
    const float* __restrict__ wq, const float* __restrict__ wk,
    const float* __restrict__ wv, const float* __restrict__ wo,
    unsigned short* __restrict__ ws) {
  const int z = blockIdx.y;
  const float* src;
  unsigned short* dst;
  unsigned nq;  // float4 count
  if (z == 0)      { src = q;  dst = ws + OFF_XQ;              nq = 1u << 20; }
  else if (z == 1) { src = k;  dst = ws + OFF_XK;              nq = 2u << 20; }
  else if (z == 2) { src = wq; dst = ws + OFF_W;               nq = 1u << 19; }
  else if (z == 3) { src = wk; dst = ws + OFF_W + (2ul << 20); nq = 1u << 19; }
  else if (z == 4) { src = wv; dst = ws + OFF_W + (4ul << 20); nq = 1u << 19; }
  else             { src = wo; dst = ws + OFF_WO;              nq = 1u << 18; }
  for (unsigned i = blockIdx.x * 256 + threadIdx.x; i < nq; i += gridDim.x * 256) {
    float4 v = ((const float4*)src)[i];
    u16x4 o = {f2bf(v.x), f2bf(v.y), f2bf(v.z), f2bf(v.w)};
    *(u16x4*)&dst[(size_t)i * 4] = o;
  }
}

// ---------------------------------------------------------------------------
// bf16 MFMA GEMM, 2-phase double-buffered staging (T3 minimum recipe):
// issue next K-tile's global_load_lds BEFORE reading current buffer, one
// barrier per K-step. 128x128 tile, BK=32, 4 waves (2x2), 4x4 frags 16x16x32.
// mode 0: bf16 scatter [nbh][seq][64]; mode 1: bf16 d-major [nbh][64][1024];
// mode 2: fp32 row-major.
// ---------------------------------------------------------------------------
__device__ __forceinline__ void gemm_mfma(const unsigned short* __restrict__ A,
                                          const unsigned short* __restrict__ B,
                                          const float* __restrict__ bias,
                                          void* __restrict__ outp, int nsrc,
                                          float scale, int mode) {
  __shared__ unsigned short As[2][4096];  // [buf][4 k-octet slabs][128 rows][8]
  __shared__ unsigned short Bs[2][4096];
  const int tid = threadIdx.x;
  const int w = tid >> 6, lane = tid & 63;
  const int wr = w >> 1, wc = w & 1;
  const long row0 = (long)blockIdx.x * 128, col0 = (long)blockIdx.y * 128;

  f32x4 acc[4][4] = {};

  const unsigned short* ga0 = A + (row0 + lane) * 1024 + w * 8;
  const unsigned short* ga1 = ga0 + 64 * 1024;
  const unsigned short* gb0 = B + (col0 + lane) * 1024 + w * 8;
  const unsigned short* gb1 = gb0 + 64 * 1024;

  const int kb = (lane >> 4) * 1024;
  const int fr = lane & 15;

  auto stage = [&](int buf, int k0) {
    gload16(ga0 + k0, &As[buf][w * 1024]);
    gload16(ga1 + k0, &As[buf][w * 1024 + 512]);
    gload16(gb0 + k0, &Bs[buf][w * 1024]);
    gload16(gb1 + k0, &Bs[buf][w * 1024 + 512]);
  };

  stage(0, 0);
  __syncthreads();  // drains vmcnt -> buf0 visible

  for (int k0 = 0; k0 < 1024; k0 += 32) {
    const int cur = (k0 >> 5) & 1;
    if (k0 + 32 < 1024) stage(cur ^ 1, k0 + 32);  // overlap with MFMA below
    bf16x8 af[4], bfr[4];
#pragma unroll
    for (int m = 0; m < 4; ++m)
      af[m] = __builtin_bit_cast(
          bf16x8, *(const u16x8*)&As[cur][kb + (wr * 64 + m * 16 + fr) * 8]);
#pragma unroll
    for (int nn = 0; nn < 4; ++nn)
      bfr[nn] = __builtin_bit_cast(
          bf16x8, *(const u16x8*)&Bs[cur][kb + (wc * 64 + nn * 16 + fr) * 8]);
#pragma unroll
    for (int m = 0; m < 4; ++m)
#pragma unroll
      for (int nn = 0; nn < 4; ++nn)
        acc[m][nn] = __builtin_amdgcn_mfma_f32_16x16x32_bf16(af[m], bfr[nn],
                                                             acc[m][nn], 0, 0, 0);
    __syncthreads();  // all reads of buf[cur] done + next buffer's loads drained
  }

  const int fq = lane >> 4;
#pragma unroll
  for (int m = 0; m < 4; ++m)
#pragma unroll
    for (int nn = 0; nn < 4; ++nn) {
      const long col = col0 + wc * 64 + nn * 16 + fr;
      const float bcol = bias[col];
#pragma unroll
      for (int r = 0; r < 4; ++r) {
        const long row = row0 + wr * 64 + m * 16 + fq * 4 + r;
        const float v = (acc[m][nn][r] + bcol) * scale;
        const long t = row >> 2, bb = row & 3;  // row = t*4 + b
        const long h = col >> 6, d = col & 63;  // col = h*64 + d
        const long nbh = ((long)nsrc * 4 + bb) * 16 + h;
        if (mode == 2)
          ((float*)outp)[row * 1024 + col] = v;
        else if (mode == 0)
          ((unsigned short*)outp)[(nbh * 1024 + t) * 64 + d] = f2bf(v);
        else
          ((unsigned short*)outp)[nbh * 65536 + d * 1024 + t] = f2bf(v);
      }
    }
}

// fused q/k/v projections, blockIdx.z = type*2 + n
__global__ __launch_bounds__(256) void proj_fused(unsigned short* __restrict__ ws,
                                                  const float* __restrict__ bq,
                                                  const float* __restrict__ bk,
                                                  const float* __restrict__ bv) {
  const int z = blockIdx.z;
  const int n = z & 1, type = z >> 1;
  const unsigned short* A =
      ws + (type == 0 ? OFF_XQ : OFF_XK + (unsigned long)n * (4ul << 20));
  const unsigned short* B = ws + OFF_W + (unsigned long)(type * 2 + n) * (1ul << 20);
  const float* bias = ((type == 0) ? bq : (type == 1) ? bk : bv) + n * 1024;
  unsigned short* out = ws + (type == 0 ? OFF_QP : (type == 1) ? OFF_KP : OFF_VP);
  const float scale = (type == 0) ? 0.125f : 1.0f;
  gemm_mfma(A, B, bias, out, n, scale, (type == 2) ? 1 : 0);
}

__global__ __launch_bounds__(256) void gemm_out(const unsigned short* __restrict__ ws_c,
                                                const float* __restrict__ bias,
                                                float* __restrict__ out) {
  gemm_mfma(ws_c + OFF_AO, ws_c + OFF_WO, bias, (void*)out, 0, 1.0f, 2);
}

// ---------------------------------------------------------------------------
// MFMA flash attention + T14 async-STAGE split: next K/V tile prefetched into
// registers during current tile's compute; ds_write after the barrier.
// Block 256 = 4 waves; wave owns 16 q-rows. Grid (16, H, B).
//   S^T = mfma(A=K, B=Q^T); row stats via 2 shfl; P->bf16->per-wave LDS;
//   O^T += mfma(A=V^T, B=P^T)  (V staged d-major).
// qp/kp: [nbh][seq][64]; vpt: [nbh][64][1024]; masks int[N,B,S] nonzero=pad.
// ao: bf16 [t*4+b][h*64+d]
// ---------------------------------------------------------------------------
__global__ __launch_bounds__(256) void attn_mfma(
    const unsigned short* __restrict__ qp, const unsigned short* __restrict__ kp,
    const unsigned short* __restrict__ vpt, const int* __restrict__ masks,
    unsigned short* __restrict__ ao) {
  __shared__ __align__(16) unsigned short Ks[64 * 72];   // [key][72]
  __shared__ __align__(16) unsigned short Vt[64 * 72];   // [d][72]
  __shared__ __align__(16) unsigned short Pl[4 * 16 * 72];  // per-wave [q][72]
  __shared__ __align__(16) float mba[2 * 1024];          // -3e38 / 0 per key

  const int tid = threadIdx.x;
  const int w = tid >> 6, l = tid & 63;
  const int g = l >> 4, q16 = l & 15;
  const int b = blockIdx.z, h = blockIdx.y;
  const int t0 = blockIdx.x * 64 + w * 16;

  // stage masks for both sources as f32 add-terms
#pragma unroll
  for (int p = 0; p < 2; ++p) {
    const int idx = tid + p * 256;            // 0..511
    const int n = idx >> 8, off = (idx & 255) * 4;
    const int4 mi = *(const int4*)&masks[((long)n * 4 + b) * 1024 + off];
    f32x4 mf = {mi.x ? -3.0e38f : 0.0f, mi.y ? -3.0e38f : 0.0f,
                mi.z ? -3.0e38f : 0.0f, mi.w ? -3.0e38f : 0.0f};
    *(f32x4*)&mba[n * 1024 + off] = mf;
  }

  float m = -3.0e38f, ls = 0.0f;
  f32x4 o[4] = {};  // O^T d-frags: d = df*16 + g*4 + r, col = qrow

  unsigned short* pw = &Pl[(w * 16 + q16) * 72];

  // T14 prefetch registers: this thread's 2 K-chunks + 2 V-chunks (16B each)
  const int r8 = tid >> 3, c8 = (tid & 7) * 8;  // chunk tid: row r8 / r8+32
  u16x8 pkA, pkB, pvA, pvB;
  auto pfetch = [&](int tt) {
    const int nn = tt >> 4, ss = (tt & 15) << 6;
    const long nbh2 = ((long)nn * 4 + b) * 16 + h;
    const unsigned short* kb2 = kp + nbh2 * 65536;
    const unsigned short* vb2 = vpt + nbh2 * 65536;
    pkA = *(const u16x8*)&kb2[(long)(ss + r8) * 64 + c8];
    pkB = *(const u16x8*)&kb2[(long)(ss + r8 + 32) * 64 + c8];
    pvA = *(const u16x8*)&vb2[(long)r8 * 1024 + ss + c8];
    pvB = *(const u16x8*)&vb2[(long)(r8 + 32) * 1024 + ss + c8];
  };
  pfetch(0);
  int tt = 0;

  for (int n = 0; n < 2; ++n) {
    const long nbh = ((long)n * 4 + b) * 16 + h;
    // Q B-frags (held in registers for the whole source)
    const unsigned short* qrp = qp + (nbh * 1024 + t0 + q16) * 64 + g * 8;
    const bf16x8 qf0 = __builtin_bit_cast(bf16x8, *(const u16x8*)&qrp[0]);
    const bf16x8 qf1 = __builtin_bit_cast(bf16x8, *(const u16x8*)&qrp[32]);
    const float* mb = &mba[n * 1024];

    for (int s0 = 0; s0 < 1024; s0 += 64) {
      __syncthreads();  // prev tile consumed (covers mask staging on 1st iter)
      // write prefetched K [64 keys][64 d] and V^T [64 d][64 keys]
      *(u16x8*)&Ks[r8 * 72 + c8] = pkA;
      *(u16x8*)&Ks[(r8 + 32) * 72 + c8] = pkB;
      *(u16x8*)&Vt[r8 * 72 + c8] = pvA;
      *(u16x8*)&Vt[(r8 + 32) * 72 + c8] = pvB;
      __syncthreads();
      if (tt + 1 < 32) pfetch(tt + 1);  // latency hides under compute below

      // QK^T (swapped): S^T key-frags
      f32x4 st[4] = {};
#pragma unroll
      for (int kf = 0; kf < 4; ++kf) {
        const bf16x8 ka0 = __builtin_bit_cast(
            bf16x8, *(const u16x8*)&Ks[(kf * 16 + q16) * 72 + g * 8]);
        const bf16x8 ka1 = __builtin_bit_cast(
            bf16x8, *(const u16x8*)&Ks[(kf * 16 + q16) * 72 + 32 + g * 8]);
        st[kf] = __builtin_amdgcn_mfma_f32_16x16x32_bf16(ka0, qf0, st[kf], 0, 0, 0);
        st[kf] = __builtin_amdgcn_mfma_f32_16x16x32_bf16(ka1, qf1, st[kf], 0, 0, 0);
      }
      // mask + row max (key = kf*16 + g*4 + r, col = qrow = q16)
      float mt = -3.0e38f;
#pragma unroll
      for (int kf = 0; kf < 4; ++kf) {
        const f32x4 mv = *(const f32x4*)&mb[s0 + kf * 16 + g * 4];
#pragma unroll
        for (int r = 0; r < 4; ++r) {
          st[kf][r] += mv[r];
          mt = fmaxf(mt, st[kf][r]);
        }
      }
      mt = fmaxf(mt, __shfl_xor(mt, 16, 64));
      mt = fmaxf(mt, __shfl_xor(mt, 32, 64));
      const float mnew = fmaxf(m, mt);
      const float corr = __expf(m - mnew);
      float ps = 0.0f;
#pragma unroll
      for (int kf = 0; kf < 4; ++kf)
#pragma unroll
        for (int r = 0; r < 4; ++r) {
          st[kf][r] = __expf(st[kf][r] - mnew);
          ps += st[kf][r];
        }
      ps += __shfl_xor(ps, 16, 64);
      ps += __shfl_xor(ps, 32, 64);
      ls = ls * corr + ps;
      m = mnew;
#pragma unroll
      for (int df = 0; df < 4; ++df)
#pragma unroll
        for (int r = 0; r < 4; ++r) o[df][r] *= corr;
      // P -> bf16 -> per-wave LDS (row q16, keys kf*16 + g*4 .. +3)
#pragma unroll
      for (int kf = 0; kf < 4; ++kf) {
        u16x4 pp = {f2bf(st[kf][0]), f2bf(st[kf][1]), f2bf(st[kf][2]),
                    f2bf(st[kf][3])};
        *(u16x4*)&pw[kf * 16 + g * 4] = pp;
      }
      // PV: O^T += V^T · P^T  (k-dim 64 keys = 2 chunks)
      const bf16x8 pb0 = __builtin_bit_cast(bf16x8, *(const u16x8*)&pw[g * 8]);
      const bf16x8 pb1 = __builtin_bit_cast(bf16x8, *(const u16x8*)&pw[32 + g * 8]);
#pragma unroll
      for (int df = 0; df < 4; ++df) {
        const bf16x8 va0 = __builtin_bit_cast(
            bf16x8, *(const u16x8*)&Vt[(df * 16 + q16) * 72 + g * 8]);
        const bf16x8 va1 = __builtin_bit_cast(
            bf16x8, *(const u16x8*)&Vt[(df * 16 + q16) * 72 + 32 + g * 8]);
        o[df] = __builtin_amdgcn_mfma_f32_16x16x32_bf16(va0, pb0, o[df], 0, 0, 0);
        o[df] = __builtin_amdgcn_mfma_f32_16x16x32_bf16(va1, pb1, o[df], 0, 0, 0);
      }
      ++tt;
    }
  }

  // epilogue: O[qrow][d], normalize; ao row = qrow*4 + b, col = h*64 + d
  const float inv = 1.0f / ls;
  unsigned short* orow = ao + ((long)(t0 + q16) * 4 + b) * 1024 + h * 64 + g * 4;
#pragma unroll
  for (int df = 0; df < 4; ++df) {
    u16x4 ov = {f2bf(o[df][0] * inv), f2bf(o[df][1] * inv),
                f2bf(o[df][2] * inv), f2bf(o[df][3] * inv)};
    *(u16x4*)&orow[df * 16] = ov;
  }
}

// ---------------------------------------------------------------------------
extern "C" void kernel_launch(void* const* d_in, const int* in_sizes, int n_in,
                              void* d_out, int out_size, void* d_ws, size_t ws_size,
                              hipStream_t stream) {
  const float* query = (const float*)d_in[0];
  const float* keys = (const float*)d_in[1];
  const int* masks = (const int*)d_in[2];
  const float* bq = (const float*)d_in[4];
  const float* bk = (const float*)d_in[6];
  const float* bv = (const float*)d_in[8];
  const float* bo = (const float*)d_in[10];

  unsigned short* ws = (unsigned short*)d_ws;  // 94 MB used
  const dim3 blk(256);

  cvt_all<<<dim3(512, 6), blk, 0, stream>>>(query, keys, (const float*)d_in[3],
                                            (const float*)d_in[5],
                                            (const float*)d_in[7],
                                            (const float*)d_in[9], ws);
  proj_fused<<<dim3(32, 8, 6), blk, 0, stream>>>(ws, bq, bk, bv);
  attn_mfma<<<dim3(16, 16, 4), blk, 0, stream>>>(
      ws + OFF_QP, ws + OFF_KP, ws + OFF_VP, masks, ws + OFF_AO);
  gemm_out<<<dim3(32, 8, 1), blk, 0, stream>>>(ws, bo, (float*)d_out);
}